// Round 1
// baseline (1222.202 us; speedup 1.0000x reference)
//
#include <hip/hip_runtime.h>

// ---------------------------------------------------------------------------
// VQ-VAE forward, fp32 baseline.
// Layout everywhere: NCL (channel-major rows of length L), matching reference.
// ---------------------------------------------------------------------------

#define WS_BUF_ELEMS (1u << 20)   // 1M floats per ping-pong buffer

// Generic 1D conv: thread = (n, co-group G, l). Weights are block-uniform ->
// scalar loads. acc[G] gives G-fold register reuse of each x value.
template<int Ci, int K, int STRIDE, int PAD, int G,
         bool RELU_IN, bool RELU_OUT, bool BIAS, bool RES>
__global__ __launch_bounds__(256) void convk(
    const float* __restrict__ in, const float* __restrict__ w,
    const float* __restrict__ b, const float* __restrict__ res,
    float* __restrict__ out, int Lin, int Lout, int Co) {
  int l   = blockIdx.x * 256 + threadIdx.x;
  int co0 = blockIdx.y * G;
  int n   = blockIdx.z;
  float acc[G];
#pragma unroll
  for (int g = 0; g < G; ++g) acc[g] = BIAS ? b[co0 + g] : 0.f;
  const float* inN = in + (size_t)n * Ci * Lin;
  const float* wp  = w + (size_t)co0 * Ci * K;
  for (int ci = 0; ci < Ci; ++ci) {
    const float* row = inN + (size_t)ci * Lin;
#pragma unroll
    for (int k = 0; k < K; ++k) {
      int li = l * STRIDE - PAD + k;
      float v = 0.f;
      if (li >= 0 && li < Lin) v = row[li];
      if (RELU_IN) v = fmaxf(v, 0.f);
#pragma unroll
      for (int g = 0; g < G; ++g)
        acc[g] = fmaf(wp[((size_t)g * Ci + ci) * K + k], v, acc[g]);
    }
  }
#pragma unroll
  for (int g = 0; g < G; ++g) {
    float o = acc[g];
    if (RES) o += res[((size_t)n * Co + co0 + g) * Lout + l];
    if (RELU_OUT) o = fmaxf(o, 0.f);
    out[((size_t)n * Co + co0 + g) * Lout + l] = o;
  }
}

// ConvTranspose1d, stride=2, pad=1, K=4, torch weight layout w[Ci][Co][4].
// Thread m produces the output pair (2m, 2m+1):
//   out[2m]   = sum_ci w[ci][o][1]*x[m] + w[ci][o][3]*x[m-1]
//   out[2m+1] = sum_ci w[ci][o][0]*x[m+1] + w[ci][o][2]*x[m]
// -> tap indices compile-time uniform (scalar weight loads), float2 stores.
template<int Ci, int G, bool RELU_IN, bool RELU_OUT>
__global__ __launch_bounds__(256) void convtk(
    const float* __restrict__ in, const float* __restrict__ w,
    const float* __restrict__ b, float* __restrict__ out,
    int Lin, int Co) {
  int m   = blockIdx.x * 256 + threadIdx.x;
  int co0 = blockIdx.y * G;
  int n   = blockIdx.z;
  int Lout = 2 * Lin;
  float acc0[G], acc1[G];
#pragma unroll
  for (int g = 0; g < G; ++g) { float bb = b[co0 + g]; acc0[g] = bb; acc1[g] = bb; }
  for (int ci = 0; ci < Ci; ++ci) {
    const float* row = in + ((size_t)n * Ci + ci) * Lin;
    float xm = row[m];
    float xl = (m > 0)       ? row[m - 1] : 0.f;
    float xr = (m + 1 < Lin) ? row[m + 1] : 0.f;
    if (RELU_IN) { xm = fmaxf(xm, 0.f); xl = fmaxf(xl, 0.f); xr = fmaxf(xr, 0.f); }
    const float* wr = w + ((size_t)ci * Co + co0) * 4;
#pragma unroll
    for (int g = 0; g < G; ++g) {
      acc0[g] = fmaf(wr[g * 4 + 1], xm, acc0[g]);
      acc0[g] = fmaf(wr[g * 4 + 3], xl, acc0[g]);
      acc1[g] = fmaf(wr[g * 4 + 0], xr, acc1[g]);
      acc1[g] = fmaf(wr[g * 4 + 2], xm, acc1[g]);
    }
  }
#pragma unroll
  for (int g = 0; g < G; ++g) {
    float o0 = acc0[g], o1 = acc1[g];
    if (RELU_OUT) { o0 = fmaxf(o0, 0.f); o1 = fmaxf(o1, 0.f); }
    float2 v = make_float2(o0, o1);
    *(float2*)(out + ((size_t)n * Co + co0 + g) * Lout + 2 * m) = v;
  }
}

// Codebook squared norms: ||e||^2 per code (512 codes, dim 64).
__global__ void enorm_k(const float* __restrict__ emb, float* __restrict__ en) {
  int e = blockIdx.x * blockDim.x + threadIdx.x;
  if (e >= 512) return;
  float s = 0.f;
  const float* r = emb + (size_t)e * 64;
  for (int c = 0; c < 64; ++c) s = fmaf(r[c], r[c], s);
  en[e] = s;
}

// VQ: block = 256 threads handles 64 consecutive t for one n.
// Stage z vectors in LDS (pad 65 -> worst 2-way bank alias = free).
// Wave cq scans codes [cq*128, cq*128+128) -> code index wave-uniform ->
// emb row reads become scalar loads. dist = ||e||^2 - 2 z.e (||z||^2 const).
__global__ __launch_bounds__(256) void vq_k(
    const float* __restrict__ z, const float* __restrict__ emb,
    const float* __restrict__ en, float* __restrict__ q) {
  __shared__ float zl[64 * 65];
  __shared__ float dred[4 * 64];
  __shared__ int   ired[4 * 64];
  __shared__ int   idxs[64];
  int n  = blockIdx.y;
  int t0 = blockIdx.x * 64;
  int tid = threadIdx.x;
  int tt = tid & 63;        // lane == vector id within tile
  int cq = tid >> 6;        // wave id 0..3 == code partition
  // load 64 vectors x 64 dims, coalesced along t
  for (int it = 0; it < 16; ++it) {
    int c = cq * 16 + it;
    zl[tt * 65 + c] = z[((size_t)n * 64 + c) * 1024 + t0 + tt];
  }
  __syncthreads();
  float zv[64];
#pragma unroll
  for (int c = 0; c < 64; ++c) zv[c] = zl[tt * 65 + c];
  float best = 1e30f; int bidx = 0;
  for (int e = cq * 128; e < cq * 128 + 128; ++e) {
    const float* er = emb + (size_t)e * 64;
    float dot = 0.f;
#pragma unroll
    for (int c = 0; c < 64; ++c) dot = fmaf(zv[c], er[c], dot);
    float d = en[e] - 2.f * dot;
    if (d < best) { best = d; bidx = e; }
  }
  dred[cq * 64 + tt] = best;
  ired[cq * 64 + tt] = bidx;
  __syncthreads();
  if (cq == 0) {
    for (int j = 1; j < 4; ++j) {
      float d = dred[j * 64 + tt]; int i2 = ired[j * 64 + tt];
      if (d < best || (d == best && i2 < bidx)) { best = d; bidx = i2; }
    }
    idxs[tt] = bidx;
  }
  __syncthreads();
  // write q[n, c, t0+tt] = emb[idx[tt]][c], coalesced along t
  for (int it = 0; it < 16; ++it) {
    int c = cq * 16 + it;
    q[((size_t)n * 64 + c) * 1024 + t0 + tt] = emb[(size_t)idxs[tt] * 64 + c];
  }
}

extern "C" void kernel_launch(void* const* d_in, const int* in_sizes, int n_in,
                              void* d_out, int out_size, void* d_ws, size_t ws_size,
                              hipStream_t stream) {
  const float* x        = (const float*)d_in[0];
  const float* enc_w1   = (const float*)d_in[1];
  const float* enc_b1   = (const float*)d_in[2];
  const float* enc_w2   = (const float*)d_in[3];
  const float* enc_b2   = (const float*)d_in[4];
  const float* enc_w3   = (const float*)d_in[5];
  const float* enc_b3   = (const float*)d_in[6];
  const float* enc_r0_w1= (const float*)d_in[7];
  const float* enc_r0_w2= (const float*)d_in[8];
  const float* enc_r1_w1= (const float*)d_in[9];
  const float* enc_r1_w2= (const float*)d_in[10];
  const float* prevq_w  = (const float*)d_in[11];
  const float* prevq_b  = (const float*)d_in[12];
  const float* emb      = (const float*)d_in[13];
  const float* dec_w1   = (const float*)d_in[14];
  const float* dec_b1   = (const float*)d_in[15];
  const float* dec_r0_w1= (const float*)d_in[16];
  const float* dec_r0_w2= (const float*)d_in[17];
  const float* dec_r1_w1= (const float*)d_in[18];
  const float* dec_r1_w2= (const float*)d_in[19];
  const float* dect1_w  = (const float*)d_in[20];
  const float* dect1_b  = (const float*)d_in[21];
  const float* dect2_w  = (const float*)d_in[22];
  const float* dect2_b  = (const float*)d_in[23];
  float* out = (float*)d_out;

  float* A  = (float*)d_ws;                    // 1M floats
  float* B  = A + WS_BUF_ELEMS;                // 1M floats
  float* C  = B + WS_BUF_ELEMS;                // 1M floats
  float* EN = C + WS_BUF_ELEMS;                // 512 floats

  dim3 blk(256);
  // --- encoder ---
  // conv1: x(16,768,4096) -> A(16,32,2048), relu, bias
  convk<768,4,2,1,8,false,true,true,false><<<dim3(8,4,16), blk, 0, stream>>>(
      x, enc_w1, enc_b1, nullptr, A, 4096, 2048, 32);
  // conv2: A -> B(16,64,1024), relu, bias
  convk<32,4,2,1,8,false,true,true,false><<<dim3(4,8,16), blk, 0, stream>>>(
      A, enc_w2, enc_b2, nullptr, B, 2048, 1024, 64);
  // conv3: B -> A(16,64,1024), bias
  convk<64,3,1,1,8,false,false,true,false><<<dim3(4,8,16), blk, 0, stream>>>(
      B, enc_w3, enc_b3, nullptr, A, 1024, 1024, 64);
  // res0: B = conv3x(relu A) [32ch]; C = conv1x(relu B) + A
  convk<64,3,1,1,8,true,false,false,false><<<dim3(4,4,16), blk, 0, stream>>>(
      A, enc_r0_w1, nullptr, nullptr, B, 1024, 1024, 32);
  convk<32,1,1,0,8,true,false,false,true><<<dim3(4,8,16), blk, 0, stream>>>(
      B, enc_r0_w2, nullptr, A, C, 1024, 1024, 64);
  // res1: B = conv3x(relu C); A = conv1x(relu B) + C
  convk<64,3,1,1,8,true,false,false,false><<<dim3(4,4,16), blk, 0, stream>>>(
      C, enc_r1_w1, nullptr, nullptr, B, 1024, 1024, 32);
  convk<32,1,1,0,8,true,false,false,true><<<dim3(4,8,16), blk, 0, stream>>>(
      B, enc_r1_w2, nullptr, C, A, 1024, 1024, 64);
  // prevq: B(z) = conv1x1(relu A) + bias   (stack's final ReLU fused as RELU_IN)
  convk<64,1,1,0,8,true,false,true,false><<<dim3(4,8,16), blk, 0, stream>>>(
      A, prevq_w, prevq_b, nullptr, B, 1024, 1024, 64);
  // --- VQ ---
  enorm_k<<<dim3(2), blk, 0, stream>>>(emb, EN);
  vq_k<<<dim3(16,16), blk, 0, stream>>>(B, emb, EN, C);   // C = q
  // --- decoder ---
  // dec conv1: C -> A, bias (no relu on input q)
  convk<64,3,1,1,8,false,false,true,false><<<dim3(4,8,16), blk, 0, stream>>>(
      C, dec_w1, dec_b1, nullptr, A, 1024, 1024, 64);
  // res0: B = conv3x(relu A); C = conv1x(relu B) + A
  convk<64,3,1,1,8,true,false,false,false><<<dim3(4,4,16), blk, 0, stream>>>(
      A, dec_r0_w1, nullptr, nullptr, B, 1024, 1024, 32);
  convk<32,1,1,0,8,true,false,false,true><<<dim3(4,8,16), blk, 0, stream>>>(
      B, dec_r0_w2, nullptr, A, C, 1024, 1024, 64);
  // res1: B = conv3x(relu C); A = conv1x(relu B) + C
  convk<64,3,1,1,8,true,false,false,false><<<dim3(4,4,16), blk, 0, stream>>>(
      C, dec_r1_w1, nullptr, nullptr, B, 1024, 1024, 32);
  convk<32,1,1,0,8,true,false,false,true><<<dim3(4,8,16), blk, 0, stream>>>(
      B, dec_r1_w2, nullptr, C, A, 1024, 1024, 64);
  // convT1: B(16,32,2048) = convT(relu A), relu out  (stack ReLU fused in)
  convtk<64,4,true,true><<<dim3(4,8,16), blk, 0, stream>>>(
      A, dect1_w, dect1_b, B, 1024, 32);
  // convT2: out(16,64,4096) = convT(B)
  convtk<32,4,false,false><<<dim3(8,16,16), blk, 0, stream>>>(
      B, dect2_w, dect2_b, out, 2048, 64);
}

// Round 2
// 1051.466 us; speedup vs baseline: 1.1624x; 1.1624x over previous
//
#include <hip/hip_runtime.h>

// ---------------------------------------------------------------------------
// VQ-VAE forward. conv1 (768->32, k4 s2) done as split-fp16 MFMA GEMM
// (fp32-accurate via x=h+l*2^-11, w=wh+wl*2^-11, 3 MFMA products).
// Rest of pipeline: fp32 direct convs (latency-bound; G halved for 2x waves).
// ---------------------------------------------------------------------------

#define WS_BUF_ELEMS (1u << 20)   // 1M floats per ping-pong buffer

typedef _Float16 half8 __attribute__((ext_vector_type(8)));
typedef float f32x4 __attribute__((ext_vector_type(4)));

// Generic 1D conv: thread = (n, co-group G, l). Weights block-uniform (SGPR).
template<int Ci, int K, int STRIDE, int PAD, int G,
         bool RELU_IN, bool RELU_OUT, bool BIAS, bool RES>
__global__ __launch_bounds__(256) void convk(
    const float* __restrict__ in, const float* __restrict__ w,
    const float* __restrict__ b, const float* __restrict__ res,
    float* __restrict__ out, int Lin, int Lout, int Co) {
  int l   = blockIdx.x * 256 + threadIdx.x;
  int co0 = blockIdx.y * G;
  int n   = blockIdx.z;
  float acc[G];
#pragma unroll
  for (int g = 0; g < G; ++g) acc[g] = BIAS ? b[co0 + g] : 0.f;
  const float* inN = in + (size_t)n * Ci * Lin;
  const float* wp  = w + (size_t)co0 * Ci * K;
  for (int ci = 0; ci < Ci; ++ci) {
    const float* row = inN + (size_t)ci * Lin;
#pragma unroll
    for (int k = 0; k < K; ++k) {
      int li = l * STRIDE - PAD + k;
      float v = 0.f;
      if (li >= 0 && li < Lin) v = row[li];
      if (RELU_IN) v = fmaxf(v, 0.f);
#pragma unroll
      for (int g = 0; g < G; ++g)
        acc[g] = fmaf(wp[((size_t)g * Ci + ci) * K + k], v, acc[g]);
    }
  }
#pragma unroll
  for (int g = 0; g < G; ++g) {
    float o = acc[g];
    if (RES) o += res[((size_t)n * Co + co0 + g) * Lout + l];
    if (RELU_OUT) o = fmaxf(o, 0.f);
    out[((size_t)n * Co + co0 + g) * Lout + l] = o;
  }
}

// ConvTranspose1d, stride=2, pad=1, K=4, torch weight layout w[Ci][Co][4].
template<int Ci, int G, bool RELU_IN, bool RELU_OUT>
__global__ __launch_bounds__(256) void convtk(
    const float* __restrict__ in, const float* __restrict__ w,
    const float* __restrict__ b, float* __restrict__ out,
    int Lin, int Co) {
  int m   = blockIdx.x * 256 + threadIdx.x;
  int co0 = blockIdx.y * G;
  int n   = blockIdx.z;
  int Lout = 2 * Lin;
  float acc0[G], acc1[G];
#pragma unroll
  for (int g = 0; g < G; ++g) { float bb = b[co0 + g]; acc0[g] = bb; acc1[g] = bb; }
  for (int ci = 0; ci < Ci; ++ci) {
    const float* row = in + ((size_t)n * Ci + ci) * Lin;
    float xm = row[m];
    float xl = (m > 0)       ? row[m - 1] : 0.f;
    float xr = (m + 1 < Lin) ? row[m + 1] : 0.f;
    if (RELU_IN) { xm = fmaxf(xm, 0.f); xl = fmaxf(xl, 0.f); xr = fmaxf(xr, 0.f); }
    const float* wr = w + ((size_t)ci * Co + co0) * 4;
#pragma unroll
    for (int g = 0; g < G; ++g) {
      acc0[g] = fmaf(wr[g * 4 + 1], xm, acc0[g]);
      acc0[g] = fmaf(wr[g * 4 + 3], xl, acc0[g]);
      acc1[g] = fmaf(wr[g * 4 + 0], xr, acc1[g]);
      acc1[g] = fmaf(wr[g * 4 + 2], xm, acc1[g]);
    }
  }
#pragma unroll
  for (int g = 0; g < G; ++g) {
    float o0 = acc0[g], o1 = acc1[g];
    if (RELU_OUT) { o0 = fmaxf(o0, 0.f); o1 = fmaxf(o1, 0.f); }
    float2 v = make_float2(o0, o1);
    *(float2*)(out + ((size_t)n * Co + co0 + g) * Lout + 2 * m) = v;
  }
}

// --------------------- conv1 as split-fp16 MFMA GEMM -----------------------
// Weight prep: w(32,768,4) fp32 -> wh/wl[chunk=48][co=32][kk=64] fp16,
// kk = ci_local*4 + tap (ci_local in [0,16)).  wl prescaled by 2^11.
__global__ void wsplit_k(const float* __restrict__ w,
                         _Float16* __restrict__ wh, _Float16* __restrict__ wl) {
  int idx = blockIdx.x * 256 + threadIdx.x;
  if (idx >= 32 * 3072) return;
  int co = idx / 3072, t = idx % 3072;     // t = ci*4+tap = c*64+kk
  int c = t >> 6, kk = t & 63;
  float v = w[idx];
  _Float16 h = (_Float16)v;
  size_t o = ((size_t)c * 32 + co) * 64 + kk;
  wh[o] = h;
  wl[o] = (_Float16)((v - (float)h) * 2048.0f);
}

// Block: 256 thr = 4 waves, tile = 128 positions x 32 co for one n.
// K-loop: 48 chunks of 16 ci (kk width 64). A staged fp32->fp16 split in LDS,
// B (weights) copied from prepped fp16. mfma_f32_16x16x32_f16, layouts:
//   A[m=lane&15][k=quad*8+j], B[k=quad*8+j][n=lane&15],
//   D: col(lane&15)=n, row(quad*4+reg)=m.   (m89/m91/m122-verified)
__global__ __launch_bounds__(256) void conv1_mfma(
    const float* __restrict__ x, const _Float16* __restrict__ wh,
    const _Float16* __restrict__ wl, const float* __restrict__ bias,
    float* __restrict__ out) {
  constexpr int ROWP = 272;                // A row pitch (f16), 258 used
  __shared__ _Float16 Ah[16 * ROWP], Al[16 * ROWP];
  __shared__ _Float16 Bh[32 * 68],  Bl[32 * 68];   // +4 f16 pad -> 2-way banks
  const int tid  = threadIdx.x;
  const int wave = tid >> 6, lane = tid & 63;
  const int lm = lane & 15, quad = lane >> 4;
  const int l0 = blockIdx.x * 128;
  const int n  = blockIdx.y;
  f32x4 acc1[2][2], acc2[2][2];
#pragma unroll
  for (int a = 0; a < 2; ++a)
#pragma unroll
    for (int bb = 0; bb < 2; ++bb)
#pragma unroll
      for (int r = 0; r < 4; ++r) { acc1[a][bb][r] = 0.f; acc2[a][bb][r] = 0.f; }
  const int srow = tid >> 4, scol0 = tid & 15;
  const float* xn = x + (size_t)n * 768 * 4096;
  const int base = 2 * l0 - 1;

  for (int c = 0; c < 48; ++c) {
    __syncthreads();
    { // stage A: 16 ci rows x 258 positions, fp32 -> (h, l*2^11) fp16
      const float* xr = xn + (size_t)(c * 16 + srow) * 4096;
      _Float16* ah = Ah + srow * ROWP;
      _Float16* al = Al + srow * ROWP;
#pragma unroll
      for (int i = 0; i < 17; ++i) {
        int col = scol0 + 16 * i;
        if (col < 258) {
          int p = base + col;
          float v = (p >= 0 && p < 4096) ? xr[p] : 0.f;
          _Float16 h = (_Float16)v;
          ah[col] = h;
          al[col] = (_Float16)((v - (float)h) * 2048.0f);
        }
      }
    }
    { // stage B: 32co x 64kk fp16 x2 planes (4 KB each)
      const uint2* gh = (const uint2*)(wh + (size_t)c * 2048);
      const uint2* gl = (const uint2*)(wl + (size_t)c * 2048);
#pragma unroll
      for (int it = 0; it < 2; ++it) {
        int idx = tid + it * 256;          // 512 chunks of 4 f16
        int co = idx >> 4, s = idx & 15;
        *(uint2*)(Bh + co * 68 + s * 4) = gh[idx];
        *(uint2*)(Bl + co * 68 + s * 4) = gl[idx];
      }
    }
    __syncthreads();
#pragma unroll
    for (int ks = 0; ks < 2; ++ks) {       // two K=32 steps per chunk
      half8 aH[2], aL[2], bH[2], bL[2];
#pragma unroll
      for (int mt = 0; mt < 2; ++mt) {     // A frags: j 0..3 row r, 4..7 row r+1
        int r = ks * 8 + quad * 2;
        int mloc = wave * 32 + mt * 16 + lm;
        const int* p0h = (const int*)(Ah + r * ROWP + 2 * mloc);
        const int* p1h = (const int*)(Ah + (r + 1) * ROWP + 2 * mloc);
        const int* p0l = (const int*)(Al + r * ROWP + 2 * mloc);
        const int* p1l = (const int*)(Al + (r + 1) * ROWP + 2 * mloc);
        union { int i[4]; half8 h; } uh, ul;
        uh.i[0] = p0h[0]; uh.i[1] = p0h[1]; uh.i[2] = p1h[0]; uh.i[3] = p1h[1];
        ul.i[0] = p0l[0]; ul.i[1] = p0l[1]; ul.i[2] = p1l[0]; ul.i[3] = p1l[1];
        aH[mt] = uh.h; aL[mt] = ul.h;
      }
#pragma unroll
      for (int nt = 0; nt < 2; ++nt) {     // B frags: 8 consecutive kk
        int co = nt * 16 + lm;
        const uint2* ph = (const uint2*)(Bh + co * 68 + ks * 32 + quad * 8);
        const uint2* pl = (const uint2*)(Bl + co * 68 + ks * 32 + quad * 8);
        union { uint2 q[2]; half8 h; } vh, vl;
        vh.q[0] = ph[0]; vh.q[1] = ph[1];
        vl.q[0] = pl[0]; vl.q[1] = pl[1];
        bH[nt] = vh.h; bL[nt] = vl.h;
      }
#pragma unroll
      for (int mt = 0; mt < 2; ++mt)
#pragma unroll
        for (int nt = 0; nt < 2; ++nt) {
          acc1[mt][nt] = __builtin_amdgcn_mfma_f32_16x16x32_f16(
              aH[mt], bH[nt], acc1[mt][nt], 0, 0, 0);
          acc2[mt][nt] = __builtin_amdgcn_mfma_f32_16x16x32_f16(
              aH[mt], bL[nt], acc2[mt][nt], 0, 0, 0);
          acc2[mt][nt] = __builtin_amdgcn_mfma_f32_16x16x32_f16(
              aL[mt], bH[nt], acc2[mt][nt], 0, 0, 0);
        }
    }
  }
  // epilogue: out[n][co][pos] = relu(acc1 + acc2/2048 + bias)
#pragma unroll
  for (int nt = 0; nt < 2; ++nt) {
    int co = nt * 16 + lm;
    float bv = bias[co];
    float* op = out + ((size_t)n * 32 + co) * 2048;
#pragma unroll
    for (int mt = 0; mt < 2; ++mt)
#pragma unroll
      for (int r = 0; r < 4; ++r) {
        int pos = l0 + wave * 32 + mt * 16 + quad * 4 + r;
        float v = acc1[mt][nt][r] + acc2[mt][nt][r] * (1.0f / 2048.0f) + bv;
        op[pos] = fmaxf(v, 0.f);
      }
  }
}

// Codebook squared norms
__global__ void enorm_k(const float* __restrict__ emb, float* __restrict__ en) {
  int e = blockIdx.x * blockDim.x + threadIdx.x;
  if (e >= 512) return;
  float s = 0.f;
  const float* r = emb + (size_t)e * 64;
  for (int c = 0; c < 64; ++c) s = fmaf(r[c], r[c], s);
  en[e] = s;
}

// VQ (unchanged from round 0, fp32-exact distances)
__global__ __launch_bounds__(256) void vq_k(
    const float* __restrict__ z, const float* __restrict__ emb,
    const float* __restrict__ en, float* __restrict__ q) {
  __shared__ float zl[64 * 65];
  __shared__ float dred[4 * 64];
  __shared__ int   ired[4 * 64];
  __shared__ int   idxs[64];
  int n  = blockIdx.y;
  int t0 = blockIdx.x * 64;
  int tid = threadIdx.x;
  int tt = tid & 63;
  int cq = tid >> 6;
  for (int it = 0; it < 16; ++it) {
    int c = cq * 16 + it;
    zl[tt * 65 + c] = z[((size_t)n * 64 + c) * 1024 + t0 + tt];
  }
  __syncthreads();
  float zv[64];
#pragma unroll
  for (int c = 0; c < 64; ++c) zv[c] = zl[tt * 65 + c];
  float best = 1e30f; int bidx = 0;
  for (int e = cq * 128; e < cq * 128 + 128; ++e) {
    const float* er = emb + (size_t)e * 64;
    float dot = 0.f;
#pragma unroll
    for (int c = 0; c < 64; ++c) dot = fmaf(zv[c], er[c], dot);
    float d = en[e] - 2.f * dot;
    if (d < best) { best = d; bidx = e; }
  }
  dred[cq * 64 + tt] = best;
  ired[cq * 64 + tt] = bidx;
  __syncthreads();
  if (cq == 0) {
    for (int j = 1; j < 4; ++j) {
      float d = dred[j * 64 + tt]; int i2 = ired[j * 64 + tt];
      if (d < best || (d == best && i2 < bidx)) { best = d; bidx = i2; }
    }
    idxs[tt] = bidx;
  }
  __syncthreads();
  for (int it = 0; it < 16; ++it) {
    int c = cq * 16 + it;
    q[((size_t)n * 64 + c) * 1024 + t0 + tt] = emb[(size_t)idxs[tt] * 64 + c];
  }
}

extern "C" void kernel_launch(void* const* d_in, const int* in_sizes, int n_in,
                              void* d_out, int out_size, void* d_ws, size_t ws_size,
                              hipStream_t stream) {
  const float* x        = (const float*)d_in[0];
  const float* enc_w1   = (const float*)d_in[1];
  const float* enc_b1   = (const float*)d_in[2];
  const float* enc_w2   = (const float*)d_in[3];
  const float* enc_b2   = (const float*)d_in[4];
  const float* enc_w3   = (const float*)d_in[5];
  const float* enc_b3   = (const float*)d_in[6];
  const float* enc_r0_w1= (const float*)d_in[7];
  const float* enc_r0_w2= (const float*)d_in[8];
  const float* enc_r1_w1= (const float*)d_in[9];
  const float* enc_r1_w2= (const float*)d_in[10];
  const float* prevq_w  = (const float*)d_in[11];
  const float* prevq_b  = (const float*)d_in[12];
  const float* emb      = (const float*)d_in[13];
  const float* dec_w1   = (const float*)d_in[14];
  const float* dec_b1   = (const float*)d_in[15];
  const float* dec_r0_w1= (const float*)d_in[16];
  const float* dec_r0_w2= (const float*)d_in[17];
  const float* dec_r1_w1= (const float*)d_in[18];
  const float* dec_r1_w2= (const float*)d_in[19];
  const float* dect1_w  = (const float*)d_in[20];
  const float* dect1_b  = (const float*)d_in[21];
  const float* dect2_w  = (const float*)d_in[22];
  const float* dect2_b  = (const float*)d_in[23];
  float* out = (float*)d_out;

  float* A  = (float*)d_ws;
  float* B  = A + WS_BUF_ELEMS;
  float* C  = B + WS_BUF_ELEMS;
  float* EN = C + WS_BUF_ELEMS;
  // conv1 split weights overlay the C buffer (C first written after conv1)
  _Float16* WH = (_Float16*)C;
  _Float16* WL = WH + 48 * 32 * 64;

  dim3 blk(256);
  // --- encoder ---
  wsplit_k<<<dim3(384), blk, 0, stream>>>(enc_w1, WH, WL);
  conv1_mfma<<<dim3(16, 16), blk, 0, stream>>>(x, WH, WL, enc_b1, A);
  // conv2: A(16,32,2048) -> B(16,64,1024), relu, bias
  convk<32,4,2,1,4,false,true,true,false><<<dim3(4,16,16), blk, 0, stream>>>(
      A, enc_w2, enc_b2, nullptr, B, 2048, 1024, 64);
  // conv3: B -> A(16,64,1024), bias
  convk<64,3,1,1,4,false,false,true,false><<<dim3(4,16,16), blk, 0, stream>>>(
      B, enc_w3, enc_b3, nullptr, A, 1024, 1024, 64);
  // res0
  convk<64,3,1,1,4,true,false,false,false><<<dim3(4,8,16), blk, 0, stream>>>(
      A, enc_r0_w1, nullptr, nullptr, B, 1024, 1024, 32);
  convk<32,1,1,0,4,true,false,false,true><<<dim3(4,16,16), blk, 0, stream>>>(
      B, enc_r0_w2, nullptr, A, C, 1024, 1024, 64);
  // res1
  convk<64,3,1,1,4,true,false,false,false><<<dim3(4,8,16), blk, 0, stream>>>(
      C, enc_r1_w1, nullptr, nullptr, B, 1024, 1024, 32);
  convk<32,1,1,0,4,true,false,false,true><<<dim3(4,16,16), blk, 0, stream>>>(
      B, enc_r1_w2, nullptr, C, A, 1024, 1024, 64);
  // prevq (stack's final ReLU fused as RELU_IN)
  convk<64,1,1,0,4,true,false,true,false><<<dim3(4,16,16), blk, 0, stream>>>(
      A, prevq_w, prevq_b, nullptr, B, 1024, 1024, 64);
  // --- VQ ---
  enorm_k<<<dim3(2), blk, 0, stream>>>(emb, EN);
  vq_k<<<dim3(16,16), blk, 0, stream>>>(B, emb, EN, C);   // C = q
  // --- decoder ---
  convk<64,3,1,1,4,false,false,true,false><<<dim3(4,16,16), blk, 0, stream>>>(
      C, dec_w1, dec_b1, nullptr, A, 1024, 1024, 64);
  convk<64,3,1,1,4,true,false,false,false><<<dim3(4,8,16), blk, 0, stream>>>(
      A, dec_r0_w1, nullptr, nullptr, B, 1024, 1024, 32);
  convk<32,1,1,0,4,true,false,false,true><<<dim3(4,16,16), blk, 0, stream>>>(
      B, dec_r0_w2, nullptr, A, C, 1024, 1024, 64);
  convk<64,3,1,1,4,true,false,false,false><<<dim3(4,8,16), blk, 0, stream>>>(
      C, dec_r1_w1, nullptr, nullptr, B, 1024, 1024, 32);
  convk<32,1,1,0,4,true,false,false,true><<<dim3(4,16,16), blk, 0, stream>>>(
      B, dec_r1_w2, nullptr, C, A, 1024, 1024, 64);
  // convT1: B(16,32,2048) = convT(relu A), relu out
  convtk<64,2,true,true><<<dim3(4,16,16), blk, 0, stream>>>(
      A, dect1_w, dect1_b, B, 1024, 32);
  // convT2: out(16,64,4096) = convT(B)
  convtk<32,4,false,false><<<dim3(8,16,16), blk, 0, stream>>>(
      B, dect2_w, dect2_b, out, 2048, 64);
}

// Round 3
// 943.601 us; speedup vs baseline: 1.2953x; 1.1143x over previous
//
#include <hip/hip_runtime.h>

// ---------------------------------------------------------------------------
// VQ-VAE forward — split-fp16 MFMA everywhere.
// x = h + l*2^-11 (l prescaled by 2^11), w likewise; acc1 = h*wh,
// acc2 = h*wl + l*wh; result = acc1 + acc2/2048.  (fp32-accurate)
// Verified MFMA mapping (round 1): A[m=lane&15][k=quad*8+j] (8 consecutive k),
// B rows [n][kk] (8 consecutive kk at col n=lane&15), D col=lane&15,
// row=quad*4+reg.  kk = ci*4 + tap, tap padded to 4 with zero weights.
// ---------------------------------------------------------------------------

typedef _Float16 half8 __attribute__((ext_vector_type(8)));
typedef float f32x4 __attribute__((ext_vector_type(4)));
union H8u { half8 h; int4 i; };
union P4u { _Float16 e[4]; int2 u; };

__device__ __forceinline__ void splitf(float v, _Float16& h, _Float16& l) {
  h = (_Float16)v; l = (_Float16)((v - (float)h) * 2048.0f);
}
#define INV2048 (1.0f / 2048.0f)

// ---- prepped-weight layout offsets (f16 elements) ----
#define OFF_C1   0        // conv1  [32][3072]
#define OFF_C2   98304    // conv2  [64][128]
#define OFF_C3   106496   // conv3  [64][256]
#define OFF_ER0A 122880   // enc r0 conv3 [32][256]
#define OFF_ER0B 131072   // enc r0 1x1   [64][32]
#define OFF_ER1A 133120
#define OFF_ER1B 141312
#define OFF_PQ   143360   // prevq [64][64]
#define OFF_DW1  147456   // dec conv1 [64][256]
#define OFF_DR0A 163840
#define OFF_DR0B 172032
#define OFF_DR1A 174080
#define OFF_DR1B 182272
#define OFF_T1   184320   // convT1 [64=par*32+co][256]
#define OFF_T2   200704   // convT2 [128=par*64+co][128]
#define WTOT     217088

struct WPtrs {
  const float *c1, *c2, *c3, *er0a, *er0b, *er1a, *er1b, *pq,
              *dw1, *dr0a, *dr0b, *dr1a, *dr1b, *t1, *t2;
};

__device__ __forceinline__ int tpose_kt(int par, int tap) {
  // parity0: tap0->w3, tap1->w1 ; parity1: tap1->w2, tap2->w0
  if (par == 0) { if (tap == 0) return 3; if (tap == 1) return 1; }
  else          { if (tap == 1) return 2; if (tap == 2) return 0; }
  return -1;
}

__global__ __launch_bounds__(256) void prep_k(WPtrs P, _Float16* __restrict__ WH,
                                              _Float16* __restrict__ WL) {
  int s = blockIdx.x * 256 + threadIdx.x;
  if (s >= WTOT) return;
  float v = 0.f;
  if (s < OFF_C2) {                       // conv1: k=4, Ci=768
    int t = s, co = t / 3072, kk = t % 3072;
    v = P.c1[(co * 768 + (kk >> 2)) * 4 + (kk & 3)];
  } else if (s < OFF_C3) {                // conv2: k=4, Ci=32
    int t = s - OFF_C2, co = t >> 7, kk = t & 127;
    v = P.c2[(co * 32 + (kk >> 2)) * 4 + (kk & 3)];
  } else if (s < OFF_ER0A) {              // conv3: k=3, Ci=64
    int t = s - OFF_C3, co = t >> 8, kk = t & 255, tap = kk & 3;
    if (tap < 3) v = P.c3[(co * 64 + (kk >> 2)) * 3 + tap];
  } else if (s < OFF_ER0B) {
    int t = s - OFF_ER0A, co = t >> 8, kk = t & 255, tap = kk & 3;
    if (tap < 3) v = P.er0a[(co * 64 + (kk >> 2)) * 3 + tap];
  } else if (s < OFF_ER1A) {              // 1x1 32->64: [64][32]
    int t = s - OFF_ER0B; v = P.er0b[t];  // w[co][ci][0] contiguous == [co][ci]
  } else if (s < OFF_ER1B) {
    int t = s - OFF_ER1A, co = t >> 8, kk = t & 255, tap = kk & 3;
    if (tap < 3) v = P.er1a[(co * 64 + (kk >> 2)) * 3 + tap];
  } else if (s < OFF_PQ) {
    int t = s - OFF_ER1B; v = P.er1b[t];
  } else if (s < OFF_DW1) {               // prevq 1x1 64->64
    int t = s - OFF_PQ; v = P.pq[t];
  } else if (s < OFF_DR0A) {
    int t = s - OFF_DW1, co = t >> 8, kk = t & 255, tap = kk & 3;
    if (tap < 3) v = P.dw1[(co * 64 + (kk >> 2)) * 3 + tap];
  } else if (s < OFF_DR0B) {
    int t = s - OFF_DR0A, co = t >> 8, kk = t & 255, tap = kk & 3;
    if (tap < 3) v = P.dr0a[(co * 64 + (kk >> 2)) * 3 + tap];
  } else if (s < OFF_DR1A) {
    int t = s - OFF_DR0B; v = P.dr0b[t];
  } else if (s < OFF_DR1B) {
    int t = s - OFF_DR1A, co = t >> 8, kk = t & 255, tap = kk & 3;
    if (tap < 3) v = P.dr1a[(co * 64 + (kk >> 2)) * 3 + tap];
  } else if (s < OFF_T1) {
    int t = s - OFF_DR1B; v = P.dr1b[t];
  } else if (s < OFF_T2) {                // convT1: w (64ci,32co,4)
    int t = s - OFF_T1, nn = t >> 8, kk = t & 255;
    int par = nn >> 5, co = nn & 31, ci = kk >> 2;
    int kt = tpose_kt(par, kk & 3);
    if (kt >= 0) v = P.t1[(ci * 32 + co) * 4 + kt];
  } else {                                // convT2: w (32ci,64co,4)
    int t = s - OFF_T2, nn = t >> 7, kk = t & 127;
    int par = nn >> 6, co = nn & 63, ci = kk >> 2;
    int kt = tpose_kt(par, kk & 3);
    if (kt >= 0) v = P.t2[(ci * 64 + co) * 4 + kt];
  }
  _Float16 h, l; splitf(v, h, l);
  WH[s] = h; WL[s] = l;
}

// --------------------------- conv1 (768->32, k4 s2) -------------------------
__device__ __forceinline__ void c1_load(const float* xn, int base, int ch,
                                        int rr, int cc, float4& vv) {
  int p0 = base + cc * 4;
  const float* rp = xn + (size_t)(ch * 32 + rr) * 4096;
  if (p0 >= 0 && p0 + 3 < 4096) vv = *(const float4*)(rp + p0);
  else {
    vv.x = (p0 >= 0 && p0 < 4096) ? rp[p0] : 0.f;
    vv.y = (p0+1 >= 0 && p0+1 < 4096) ? rp[p0+1] : 0.f;
    vv.z = (p0+2 >= 0 && p0+2 < 4096) ? rp[p0+2] : 0.f;
    vv.w = (p0+3 >= 0 && p0+3 < 4096) ? rp[p0+3] : 0.f;
  }
}

__global__ __launch_bounds__(256, 2) void conv1_k(
    const float* __restrict__ x, const _Float16* __restrict__ WH,
    const _Float16* __restrict__ WL, const float* __restrict__ bias,
    float* __restrict__ out) {
  constexpr int CP = 68, AP = 136, NCH = 24;
  __shared__ float xs[2][32 * CP];
  __shared__ _Float16 Ah[2][32 * AP];
  __shared__ _Float16 Al[2][32 * AP];
  const int tid = threadIdx.x;
  const int w = tid >> 6, lane = tid & 63, lm = lane & 15, quad = lane >> 4;
  const int mt = w >> 1, nt = w & 1;
  const int m0 = blockIdx.x * 32, n = blockIdx.y;
  const int base = 2 * m0 - 1;
  const float* xn = x + (size_t)n * 768 * 4096;
  const int r0i = tid / 17, c0i = tid % 17;
  const int r1i = (256 + tid) / 17, c1i = (256 + tid) % 17;
  const int r2i = (512 + tid) / 17, c2i = (512 + tid) % 17;  // tid<32 only
  float4 v0, v1, v2;
  f32x4 acc1 = {0.f,0.f,0.f,0.f}, acc2 = {0.f,0.f,0.f,0.f};
  H8u BH[2][4], BL[2][4];
  const _Float16* bhp = WH + (size_t)(nt * 16 + lm) * 3072 + quad * 8;
  const _Float16* blp = WL + (size_t)(nt * 16 + lm) * 3072 + quad * 8;

#define C1_ISSUE(ch) { c1_load(xn, base, ch, r0i, c0i, v0); \
                       c1_load(xn, base, ch, r1i, c1i, v1); \
                       if (tid < 32) c1_load(xn, base, ch, r2i, c2i, v2); }
#define C1_WRITE(b) { *(float4*)(&xs[b][r0i * CP + c0i * 4]) = v0; \
                      *(float4*)(&xs[b][r1i * CP + c1i * 4]) = v1; \
                      if (tid < 32) *(float4*)(&xs[b][r2i * CP + c2i * 4]) = v2; }
#define C1_STAGE2(b) { _Pragma("unroll") \
  for (int it = 0; it < 4; ++it) { \
    int slot = it * 256 + tid; int ci = slot & 31, m = slot >> 5; \
    const float* xr = &xs[b][ci * CP + 2 * m]; \
    P4u ph, pl; \
    splitf(xr[0], ph.e[0], pl.e[0]); splitf(xr[1], ph.e[1], pl.e[1]); \
    splitf(xr[2], ph.e[2], pl.e[2]); splitf(xr[3], ph.e[3], pl.e[3]); \
    *(int2*)(&Ah[b][m * AP + ci * 4]) = ph.u; \
    *(int2*)(&Al[b][m * AP + ci * 4]) = pl.u; } }
#define C1_ISSUEB(ch, d) { _Pragma("unroll") \
  for (int ks = 0; ks < 4; ++ks) { \
    BH[d][ks].i = *(const int4*)(bhp + (ch) * 128 + ks * 32); \
    BL[d][ks].i = *(const int4*)(blp + (ch) * 128 + ks * 32); } }

  C1_ISSUE(0); C1_WRITE(0);
  __syncthreads();
  C1_STAGE2(0); C1_ISSUE(1); C1_ISSUEB(0, 0);
  __syncthreads();
  for (int ch = 0; ch < NCH; ++ch) {
    int b = ch & 1, d = ch & 1;
#pragma unroll
    for (int ks = 0; ks < 4; ++ks) {
      H8u ah, al;
      ah.i = *(const int4*)(&Ah[b][(mt * 16 + lm) * AP + ks * 32 + quad * 8]);
      al.i = *(const int4*)(&Al[b][(mt * 16 + lm) * AP + ks * 32 + quad * 8]);
      acc1 = __builtin_amdgcn_mfma_f32_16x16x32_f16(ah.h, BH[d][ks].h, acc1, 0, 0, 0);
      acc2 = __builtin_amdgcn_mfma_f32_16x16x32_f16(ah.h, BL[d][ks].h, acc2, 0, 0, 0);
      acc2 = __builtin_amdgcn_mfma_f32_16x16x32_f16(al.h, BH[d][ks].h, acc2, 0, 0, 0);
    }
    if (ch + 1 < NCH) {
      int nb = (ch + 1) & 1;
      C1_WRITE(nb);
      __syncthreads();
      C1_STAGE2(nb);
      if (ch + 2 < NCH) C1_ISSUE(ch + 2);
      C1_ISSUEB(ch + 1, nb);
      __syncthreads();
    }
  }
  // epilogue: relu(acc + bias)
  {
    int col = nt * 16 + lm;
    float bv = bias[col];
    float4 o;
    o.x = fmaxf(acc1[0] + acc2[0] * INV2048 + bv, 0.f);
    o.y = fmaxf(acc1[1] + acc2[1] * INV2048 + bv, 0.f);
    o.z = fmaxf(acc1[2] + acc2[2] * INV2048 + bv, 0.f);
    o.w = fmaxf(acc1[3] + acc2[3] * INV2048 + bv, 0.f);
    *(float4*)(out + ((size_t)n * 32 + col) * 2048 + m0 + mt * 16 + quad * 4) = o;
  }
#undef C1_ISSUE
#undef C1_WRITE
#undef C1_STAGE2
#undef C1_ISSUEB
}

// ------------------- generic one-shot MFMA conv (M-tile 32) -----------------
template<int CI, int KP, int NT, int STRIDE,
         bool RELU_IN, bool RELU_OUT, bool BIAS, bool TPOSE, bool RESBLK>
__global__ __launch_bounds__(256) void gconv(
    const float* __restrict__ in, const _Float16* __restrict__ WH,
    const _Float16* __restrict__ WL, const float* __restrict__ bias,
    const _Float16* __restrict__ W2H, const _Float16* __restrict__ W2L,
    float* __restrict__ out, int Lin, int Lout) {
  constexpr int CP = 32 * STRIDE + 4;
  constexpr int CP4 = CP / 4;
  constexpr int AP = KP + 8;
  constexpr int KS = KP / 32;
  constexpr int NTW = (NT == 2) ? 1 : NT / 2;
  __shared__ float xs[CI * CP];
  __shared__ _Float16 Ah[32 * AP];
  __shared__ _Float16 Al[32 * AP];
  __shared__ _Float16 A2h[RESBLK ? 32 * 40 : 1];
  __shared__ _Float16 A2l[RESBLK ? 32 * 40 : 1];
  const int tid = threadIdx.x;
  const int w = tid >> 6, lane = tid & 63, lm = lane & 15, quad = lane >> 4;
  const int mt = w >> 1, ntb = (w & 1) * NTW;
  const int m0 = blockIdx.x * 32, n = blockIdx.y;
  const int base = m0 * STRIDE - 1;
  const float* inN = in + (size_t)n * CI * Lin;
  // ---- stage1: global -> xs (raw fp32) ----
  constexpr int SLOTS = CI * CP4;
#pragma unroll
  for (int it = 0; it < (SLOTS + 255) / 256; ++it) {
    int idx = it * 256 + tid;
    if (idx < SLOTS) {
      int row = idx / CP4, c4 = idx % CP4;
      int p0 = base + c4 * 4;
      const float* rp = inN + (size_t)row * Lin;
      float4 v;
      if (p0 >= 0 && p0 + 3 < Lin) v = *(const float4*)(rp + p0);
      else {
        v.x = (p0   >= 0 && p0   < Lin) ? rp[p0]   : 0.f;
        v.y = (p0+1 >= 0 && p0+1 < Lin) ? rp[p0+1] : 0.f;
        v.z = (p0+2 >= 0 && p0+2 < Lin) ? rp[p0+2] : 0.f;
        v.w = (p0+3 >= 0 && p0+3 < Lin) ? rp[p0+3] : 0.f;
      }
      *(float4*)(&xs[row * CP + c4 * 4]) = v;
    }
  }
  __syncthreads();
  // ---- stage2: xs -> A fragments (split h/l, relu_in) ----
#pragma unroll
  for (int it = 0; it < (32 * CI) / 256; ++it) {
    int slot = it * 256 + tid;
    int ci = slot & (CI - 1), m = slot / CI;
    const float* xr = &xs[ci * CP + STRIDE * m];
    float a0 = xr[0], a1 = xr[1], a2 = xr[2], a3 = xr[3];
    if (RELU_IN) { a0 = fmaxf(a0,0.f); a1 = fmaxf(a1,0.f);
                   a2 = fmaxf(a2,0.f); a3 = fmaxf(a3,0.f); }
    P4u ph, pl;
    splitf(a0, ph.e[0], pl.e[0]); splitf(a1, ph.e[1], pl.e[1]);
    splitf(a2, ph.e[2], pl.e[2]); splitf(a3, ph.e[3], pl.e[3]);
    *(int2*)(&Ah[m * AP + ci * 4]) = ph.u;
    *(int2*)(&Al[m * AP + ci * 4]) = pl.u;
  }
  __syncthreads();
  // ---- MFMA with per-ks B prefetch from global ----
  f32x4 acc1[NTW], acc2[NTW];
#pragma unroll
  for (int j = 0; j < NTW; ++j)
#pragma unroll
    for (int r = 0; r < 4; ++r) { acc1[j][r] = 0.f; acc2[j][r] = 0.f; }
  H8u bh[2][NTW], bl[2][NTW];
#pragma unroll
  for (int j = 0; j < NTW; ++j) {
    int col = (ntb + j) * 16 + lm;
    bh[0][j].i = *(const int4*)(WH + (size_t)col * KP + quad * 8);
    bl[0][j].i = *(const int4*)(WL + (size_t)col * KP + quad * 8);
  }
#pragma unroll
  for (int ks = 0; ks < KS; ++ks) {
    int cur = ks & 1;
    if (ks + 1 < KS) {
#pragma unroll
      for (int j = 0; j < NTW; ++j) {
        int col = (ntb + j) * 16 + lm;
        bh[cur ^ 1][j].i = *(const int4*)(WH + (size_t)col * KP + (ks+1) * 32 + quad * 8);
        bl[cur ^ 1][j].i = *(const int4*)(WL + (size_t)col * KP + (ks+1) * 32 + quad * 8);
      }
    }
    H8u ah, al;
    ah.i = *(const int4*)(&Ah[(mt * 16 + lm) * AP + ks * 32 + quad * 8]);
    al.i = *(const int4*)(&Al[(mt * 16 + lm) * AP + ks * 32 + quad * 8]);
#pragma unroll
    for (int j = 0; j < NTW; ++j) {
      acc1[j] = __builtin_amdgcn_mfma_f32_16x16x32_f16(ah.h, bh[cur][j].h, acc1[j], 0,0,0);
      acc2[j] = __builtin_amdgcn_mfma_f32_16x16x32_f16(ah.h, bl[cur][j].h, acc2[j], 0,0,0);
      acc2[j] = __builtin_amdgcn_mfma_f32_16x16x32_f16(al.h, bh[cur][j].h, acc2[j], 0,0,0);
    }
  }
  if (RESBLK) {
    // h = relu(conv3), split into A2 fragments (K2=32), then 1x1 32->64, +x
    int co2 = (w & 1) * 16 + lm;
#pragma unroll
    for (int r = 0; r < 4; ++r) {
      float hv = fmaxf(acc1[0][r] + acc2[0][r] * INV2048, 0.f);
      _Float16 hh, hl; splitf(hv, hh, hl);
      int m = mt * 16 + quad * 4 + r;
      A2h[m * 40 + co2] = hh; A2l[m * 40 + co2] = hl;
    }
    __syncthreads();
    f32x4 c1[2], c2[2];
#pragma unroll
    for (int j = 0; j < 2; ++j)
#pragma unroll
      for (int r = 0; r < 4; ++r) { c1[j][r] = 0.f; c2[j][r] = 0.f; }
    H8u a2h, a2l;
    a2h.i = *(const int4*)(&A2h[(mt * 16 + lm) * 40 + quad * 8]);
    a2l.i = *(const int4*)(&A2l[(mt * 16 + lm) * 40 + quad * 8]);
    int ntb2 = (w & 1) * 2;
#pragma unroll
    for (int j = 0; j < 2; ++j) {
      int col = (ntb2 + j) * 16 + lm;
      H8u wbh, wbl;
      wbh.i = *(const int4*)(W2H + col * 32 + quad * 8);
      wbl.i = *(const int4*)(W2L + col * 32 + quad * 8);
      c1[j] = __builtin_amdgcn_mfma_f32_16x16x32_f16(a2h.h, wbh.h, c1[j], 0,0,0);
      c2[j] = __builtin_amdgcn_mfma_f32_16x16x32_f16(a2h.h, wbl.h, c2[j], 0,0,0);
      c2[j] = __builtin_amdgcn_mfma_f32_16x16x32_f16(a2l.h, wbh.h, c2[j], 0,0,0);
    }
#pragma unroll
    for (int j = 0; j < 2; ++j) {
      int col = (ntb2 + j) * 16 + lm;
      float4 o;
#pragma unroll
      for (int r = 0; r < 4; ++r) {
        int m = mt * 16 + quad * 4 + r;
        float res = xs[col * CP + m + 1];
        ((float*)&o)[r] = res + c1[j][r] + c2[j][r] * INV2048;
      }
      *(float4*)(out + ((size_t)n * 64 + col) * Lout + m0 + mt * 16 + quad * 4) = o;
    }
  } else {
    constexpr int CO = TPOSE ? NT * 8 : NT * 16;
#pragma unroll
    for (int j = 0; j < NTW; ++j) {
      int col = (ntb + j) * 16 + lm;
      int par = TPOSE ? (col / CO) : 0;
      int co  = TPOSE ? (col % CO) : col;
      float bv = BIAS ? bias[co] : 0.f;
      float vr[4];
#pragma unroll
      for (int r = 0; r < 4; ++r) {
        float v = acc1[j][r] + acc2[j][r] * INV2048 + bv;
        vr[r] = RELU_OUT ? fmaxf(v, 0.f) : v;
      }
      if (TPOSE) {
#pragma unroll
        for (int r = 0; r < 4; ++r) {
          int m = m0 + mt * 16 + quad * 4 + r;
          out[((size_t)n * CO + co) * Lout + 2 * m + par] = vr[r];
        }
      } else {
        float4 o; o.x = vr[0]; o.y = vr[1]; o.z = vr[2]; o.w = vr[3];
        *(float4*)(out + ((size_t)n * CO + co) * Lout + m0 + mt * 16 + quad * 4) = o;
      }
    }
  }
}

// ------------------------------ codebook norms ------------------------------
__global__ void enorm_k(const float* __restrict__ emb, float* __restrict__ en) {
  int e = blockIdx.x * blockDim.x + threadIdx.x;
  if (e >= 512) return;
  float s = 0.f;
  const float* r = emb + (size_t)e * 64;
  for (int c = 0; c < 64; ++c) s = fmaf(r[c], r[c], s);
  en[e] = s;
}

// ------------------ fused prevq (1x1, relu-in) + VQ -------------------------
__global__ __launch_bounds__(256) void vq_fused(
    const float* __restrict__ sIn, const _Float16* __restrict__ PQH,
    const _Float16* __restrict__ PQL, const float* __restrict__ pqb,
    const float* __restrict__ emb, const float* __restrict__ en,
    float* __restrict__ q) {
  __shared__ float xs[64 * 68];
  __shared__ _Float16 Ah[64 * 72];
  __shared__ _Float16 Al[64 * 72];
  __shared__ float zl[64 * 65];
  __shared__ float dred[4 * 64];
  __shared__ int   ired[4 * 64];
  __shared__ int   idxs[64];
  const int tid = threadIdx.x;
  const int w = tid >> 6, lane = tid & 63, lm = lane & 15, quad = lane >> 4;
  const int n = blockIdx.y, t0 = blockIdx.x * 64;
  // stage1: s tile (64ci x 64t), raw
#pragma unroll
  for (int it = 0; it < 4; ++it) {
    int idx = it * 256 + tid;
    int row = idx >> 4, c4 = idx & 15;
    float4 v = *(const float4*)(sIn + ((size_t)n * 64 + row) * 1024 + t0 + c4 * 4);
    *(float4*)(&xs[row * 68 + c4 * 4]) = v;
  }
  __syncthreads();
  // stage2: relu + split -> A[t][ci]
#pragma unroll
  for (int it = 0; it < 16; ++it) {
    int slot = it * 256 + tid;
    int ci = slot & 63, t = slot >> 6;
    float v = fmaxf(xs[ci * 68 + t], 0.f);
    _Float16 h, l; splitf(v, h, l);
    Ah[t * 72 + ci] = h; Al[t * 72 + ci] = l;
  }
  __syncthreads();
  // prevq MFMA: M=64 (wave=mt), N=64 (4 nt per wave), K=64
  f32x4 a1[4], a2[4];
#pragma unroll
  for (int j = 0; j < 4; ++j)
#pragma unroll
    for (int r = 0; r < 4; ++r) { a1[j][r] = 0.f; a2[j][r] = 0.f; }
#pragma unroll
  for (int ks = 0; ks < 2; ++ks) {
    H8u ah, al;
    ah.i = *(const int4*)(&Ah[(w * 16 + lm) * 72 + ks * 32 + quad * 8]);
    al.i = *(const int4*)(&Al[(w * 16 + lm) * 72 + ks * 32 + quad * 8]);
#pragma unroll
    for (int j = 0; j < 4; ++j) {
      int col = j * 16 + lm;
      H8u bh, bl;
      bh.i = *(const int4*)(PQH + col * 64 + ks * 32 + quad * 8);
      bl.i = *(const int4*)(PQL + col * 64 + ks * 32 + quad * 8);
      a1[j] = __builtin_amdgcn_mfma_f32_16x16x32_f16(ah.h, bh.h, a1[j], 0,0,0);
      a2[j] = __builtin_amdgcn_mfma_f32_16x16x32_f16(ah.h, bl.h, a2[j], 0,0,0);
      a2[j] = __builtin_amdgcn_mfma_f32_16x16x32_f16(al.h, bh.h, a2[j], 0,0,0);
    }
  }
#pragma unroll
  for (int j = 0; j < 4; ++j) {
    int col = j * 16 + lm;
    float bv = pqb[col];
#pragma unroll
    for (int r = 0; r < 4; ++r) {
      int t = w * 16 + quad * 4 + r;
      zl[t * 65 + col] = a1[j][r] + a2[j][r] * INV2048 + bv;
    }
  }
  __syncthreads();
  // VQ search (round-1-verified logic)
  int tt = tid & 63, cq = tid >> 6;
  float zv[64];
#pragma unroll
  for (int c = 0; c < 64; ++c) zv[c] = zl[tt * 65 + c];
  float best = 1e30f; int bidx = 0;
  for (int e = cq * 128; e < cq * 128 + 128; ++e) {
    const float* er = emb + (size_t)e * 64;
    float dot = 0.f;
#pragma unroll
    for (int c = 0; c < 64; ++c) dot = fmaf(zv[c], er[c], dot);
    float d = en[e] - 2.f * dot;
    if (d < best) { best = d; bidx = e; }
  }
  dred[cq * 64 + tt] = best;
  ired[cq * 64 + tt] = bidx;
  __syncthreads();
  if (cq == 0) {
    for (int j = 1; j < 4; ++j) {
      float d = dred[j * 64 + tt]; int i2 = ired[j * 64 + tt];
      if (d < best || (d == best && i2 < bidx)) { best = d; bidx = i2; }
    }
    idxs[tt] = bidx;
  }
  __syncthreads();
  for (int it = 0; it < 16; ++it) {
    int c = cq * 16 + it;
    q[((size_t)n * 64 + c) * 1024 + t0 + tt] = emb[(size_t)idxs[tt] * 64 + c];
  }
}

// ---------------------------------------------------------------------------
extern "C" void kernel_launch(void* const* d_in, const int* in_sizes, int n_in,
                              void* d_out, int out_size, void* d_ws, size_t ws_size,
                              hipStream_t stream) {
  const float* x        = (const float*)d_in[0];
  const float* enc_b1   = (const float*)d_in[2];
  const float* enc_b2   = (const float*)d_in[4];
  const float* enc_b3   = (const float*)d_in[6];
  const float* prevq_b  = (const float*)d_in[12];
  const float* emb      = (const float*)d_in[13];
  const float* dec_b1   = (const float*)d_in[15];
  const float* dect1_b  = (const float*)d_in[21];
  const float* dect2_b  = (const float*)d_in[23];
  float* out = (float*)d_out;

  WPtrs P;
  P.c1  = (const float*)d_in[1];  P.c2  = (const float*)d_in[3];
  P.c3  = (const float*)d_in[5];  P.er0a = (const float*)d_in[7];
  P.er0b = (const float*)d_in[8]; P.er1a = (const float*)d_in[9];
  P.er1b = (const float*)d_in[10]; P.pq = (const float*)d_in[11];
  P.dw1 = (const float*)d_in[14]; P.dr0a = (const float*)d_in[16];
  P.dr0b = (const float*)d_in[17]; P.dr1a = (const float*)d_in[18];
  P.dr1b = (const float*)d_in[19]; P.t1 = (const float*)d_in[20];
  P.t2  = (const float*)d_in[22];

  float* A  = (float*)d_ws;                   // 1M floats
  float* B  = A + (1u << 20);                 // 1M floats
  float* EN = B + (1u << 20);                 // 512 floats
  _Float16* WH = (_Float16*)(EN + 1024);      // WTOT f16
  _Float16* WL = WH + WTOT;

  dim3 blk(256);
  prep_k<<<dim3(WTOT / 256), blk, 0, stream>>>(P, WH, WL);
  enorm_k<<<dim3(2), blk, 0, stream>>>(emb, EN);
  // encoder
  conv1_k<<<dim3(64, 16), blk, 0, stream>>>(x, WH + OFF_C1, WL + OFF_C1, enc_b1, A);
  gconv<32,128,4,2, false,true,true, false,false><<<dim3(32,16), blk, 0, stream>>>(
      A, WH+OFF_C2, WL+OFF_C2, enc_b2, nullptr, nullptr, B, 2048, 1024);
  gconv<64,256,4,1, false,false,true, false,false><<<dim3(32,16), blk, 0, stream>>>(
      B, WH+OFF_C3, WL+OFF_C3, enc_b3, nullptr, nullptr, A, 1024, 1024);
  gconv<64,256,2,1, true,false,false, false,true><<<dim3(32,16), blk, 0, stream>>>(
      A, WH+OFF_ER0A, WL+OFF_ER0A, nullptr, WH+OFF_ER0B, WL+OFF_ER0B, B, 1024, 1024);
  gconv<64,256,2,1, true,false,false, false,true><<<dim3(32,16), blk, 0, stream>>>(
      B, WH+OFF_ER1A, WL+OFF_ER1A, nullptr, WH+OFF_ER1B, WL+OFF_ER1B, A, 1024, 1024);
  // VQ (prevq + relu fused)
  vq_fused<<<dim3(16,16), blk, 0, stream>>>(A, WH+OFF_PQ, WL+OFF_PQ, prevq_b, emb, EN, B);
  // decoder
  gconv<64,256,4,1, false,false,true, false,false><<<dim3(32,16), blk, 0, stream>>>(
      B, WH+OFF_DW1, WL+OFF_DW1, dec_b1, nullptr, nullptr, A, 1024, 1024);
  gconv<64,256,2,1, true,false,false, false,true><<<dim3(32,16), blk, 0, stream>>>(
      A, WH+OFF_DR0A, WL+OFF_DR0A, nullptr, WH+OFF_DR0B, WL+OFF_DR0B, B, 1024, 1024);
  gconv<64,256,2,1, true,false,false, false,true><<<dim3(32,16), blk, 0, stream>>>(
      B, WH+OFF_DR1A, WL+OFF_DR1A, nullptr, WH+OFF_DR1B, WL+OFF_DR1B, A, 1024, 1024);
  gconv<64,256,4,1, true,true,true, true,false><<<dim3(32,16), blk, 0, stream>>>(
      A, WH+OFF_T1, WL+OFF_T1, dect1_b, nullptr, nullptr, B, 1024, 2048);
  gconv<32,128,8,1, false,false,true, true,false><<<dim3(64,16), blk, 0, stream>>>(
      B, WH+OFF_T2, WL+OFF_T2, dect2_b, nullptr, nullptr, out, 2048, 4096);
}

// Round 4
// 681.811 us; speedup vs baseline: 1.7926x; 1.3840x over previous
//
#include <hip/hip_runtime.h>

// ---------------------------------------------------------------------------
// VQ-VAE forward — split-fp16 MFMA everywhere.
// x = h + l*2^-11 (l prescaled by 2^11), w likewise; acc1 = h*wh,
// acc2 = h*wl + l*wh; result = acc1 + acc2/2048.  (fp32-accurate)
// Verified MFMA mapping: A[m=lane&15][k=quad*8+j] (8 consecutive k),
// B rows [n][kk] (8 consecutive kk at col n=lane&15), D col=lane&15,
// row=quad*4+reg.  kk = ci*4 + tap, tap padded to 4 with zero weights.
// R3 lesson: NEVER index register arrays with runtime values (BH[d] spilled
// to scratch -> 766 MB of HBM writes). All buffer indices now compile-time.
// ---------------------------------------------------------------------------

typedef _Float16 half8 __attribute__((ext_vector_type(8)));
typedef float f32x4 __attribute__((ext_vector_type(4)));
union H8u { half8 h; int4 i; };
union P4u { _Float16 e[4]; int2 u; };

__device__ __forceinline__ void splitf(float v, _Float16& h, _Float16& l) {
  h = (_Float16)v; l = (_Float16)((v - (float)h) * 2048.0f);
}
#define INV2048 (1.0f / 2048.0f)

// ---- prepped-weight layout offsets (f16 elements) ----
#define OFF_C1   0        // conv1  [32][3072]
#define OFF_C2   98304    // conv2  [64][128]
#define OFF_C3   106496   // conv3  [64][256]
#define OFF_ER0A 122880   // enc r0 conv3 [32][256]
#define OFF_ER0B 131072   // enc r0 1x1   [64][32]
#define OFF_ER1A 133120
#define OFF_ER1B 141312
#define OFF_PQ   143360   // prevq [64][64]
#define OFF_DW1  147456   // dec conv1 [64][256]
#define OFF_DR0A 163840
#define OFF_DR0B 172032
#define OFF_DR1A 174080
#define OFF_DR1B 182272
#define OFF_T1   184320   // convT1 [64=par*32+co][256]
#define OFF_T2   200704   // convT2 [128=par*64+co][128]
#define WTOT     217088

struct WPtrs {
  const float *c1, *c2, *c3, *er0a, *er0b, *er1a, *er1b, *pq,
              *dw1, *dr0a, *dr0b, *dr1a, *dr1b, *t1, *t2;
};

__device__ __forceinline__ int tpose_kt(int par, int tap) {
  if (par == 0) { if (tap == 0) return 3; if (tap == 1) return 1; }
  else          { if (tap == 1) return 2; if (tap == 2) return 0; }
  return -1;
}

__global__ __launch_bounds__(256) void prep_k(WPtrs P, _Float16* __restrict__ WH,
                                              _Float16* __restrict__ WL) {
  int s = blockIdx.x * 256 + threadIdx.x;
  if (s >= WTOT) return;
  float v = 0.f;
  if (s < OFF_C2) {
    int t = s, co = t / 3072, kk = t % 3072;
    v = P.c1[(co * 768 + (kk >> 2)) * 4 + (kk & 3)];
  } else if (s < OFF_C3) {
    int t = s - OFF_C2, co = t >> 7, kk = t & 127;
    v = P.c2[(co * 32 + (kk >> 2)) * 4 + (kk & 3)];
  } else if (s < OFF_ER0A) {
    int t = s - OFF_C3, co = t >> 8, kk = t & 255, tap = kk & 3;
    if (tap < 3) v = P.c3[(co * 64 + (kk >> 2)) * 3 + tap];
  } else if (s < OFF_ER0B) {
    int t = s - OFF_ER0A, co = t >> 8, kk = t & 255, tap = kk & 3;
    if (tap < 3) v = P.er0a[(co * 64 + (kk >> 2)) * 3 + tap];
  } else if (s < OFF_ER1A) {
    int t = s - OFF_ER0B; v = P.er0b[t];
  } else if (s < OFF_ER1B) {
    int t = s - OFF_ER1A, co = t >> 8, kk = t & 255, tap = kk & 3;
    if (tap < 3) v = P.er1a[(co * 64 + (kk >> 2)) * 3 + tap];
  } else if (s < OFF_PQ) {
    int t = s - OFF_ER1B; v = P.er1b[t];
  } else if (s < OFF_DW1) {
    int t = s - OFF_PQ; v = P.pq[t];
  } else if (s < OFF_DR0A) {
    int t = s - OFF_DW1, co = t >> 8, kk = t & 255, tap = kk & 3;
    if (tap < 3) v = P.dw1[(co * 64 + (kk >> 2)) * 3 + tap];
  } else if (s < OFF_DR0B) {
    int t = s - OFF_DR0A, co = t >> 8, kk = t & 255, tap = kk & 3;
    if (tap < 3) v = P.dr0a[(co * 64 + (kk >> 2)) * 3 + tap];
  } else if (s < OFF_DR1A) {
    int t = s - OFF_DR0B; v = P.dr0b[t];
  } else if (s < OFF_DR1B) {
    int t = s - OFF_DR1A, co = t >> 8, kk = t & 255, tap = kk & 3;
    if (tap < 3) v = P.dr1a[(co * 64 + (kk >> 2)) * 3 + tap];
  } else if (s < OFF_T1) {
    int t = s - OFF_DR1B; v = P.dr1b[t];
  } else if (s < OFF_T2) {
    int t = s - OFF_T1, nn = t >> 8, kk = t & 255;
    int par = nn >> 5, co = nn & 31, ci = kk >> 2;
    int kt = tpose_kt(par, kk & 3);
    if (kt >= 0) v = P.t1[(ci * 32 + co) * 4 + kt];
  } else {
    int t = s - OFF_T2, nn = t >> 7, kk = t & 127;
    int par = nn >> 6, co = nn & 63, ci = kk >> 2;
    int kt = tpose_kt(par, kk & 3);
    if (kt >= 0) v = P.t2[(ci * 64 + co) * 4 + kt];
  }
  _Float16 h, l; splitf(v, h, l);
  WH[s] = h; WL[s] = l;
}

// --------------------------- conv1 (768->32, k4 s2) -------------------------
__device__ __forceinline__ void c1_load(const float* xn, int base, int ch,
                                        int rr, int cc, float4& vv) {
  int p0 = base + cc * 4;
  const float* rp = xn + (size_t)(ch * 32 + rr) * 4096;
  if (p0 >= 0 && p0 + 3 < 4096) vv = *(const float4*)(rp + p0);
  else {
    vv.x = (p0 >= 0 && p0 < 4096) ? rp[p0] : 0.f;
    vv.y = (p0+1 >= 0 && p0+1 < 4096) ? rp[p0+1] : 0.f;
    vv.z = (p0+2 >= 0 && p0+2 < 4096) ? rp[p0+2] : 0.f;
    vv.w = (p0+3 >= 0 && p0+3 < 4096) ? rp[p0+3] : 0.f;
  }
}

__global__ __launch_bounds__(256, 2) void conv1_k(
    const float* __restrict__ x, const _Float16* __restrict__ WH,
    const _Float16* __restrict__ WL, const float* __restrict__ bias,
    float* __restrict__ out) {
  constexpr int CP = 68, AP = 136, NCH = 24;
  __shared__ float xs0[32 * CP], xs1[32 * CP];
  __shared__ _Float16 Ah0[32 * AP], Al0[32 * AP];
  __shared__ _Float16 Ah1[32 * AP], Al1[32 * AP];
  const int tid = threadIdx.x;
  const int w = tid >> 6, lane = tid & 63, lm = lane & 15, quad = lane >> 4;
  const int mt = w >> 1, nt = w & 1;
  const int m0 = blockIdx.x * 32, n = blockIdx.y;
  const int base = 2 * m0 - 1;
  const float* xn = x + (size_t)n * 768 * 4096;
  const int r0i = tid / 17, c0i = tid % 17;
  const int r1i = (256 + tid) / 17, c1i = (256 + tid) % 17;
  const int r2i = (512 + tid) / 17, c2i = (512 + tid) % 17;  // tid<32 only
  float4 v0, v1, v2;
  f32x4 acc1 = {0.f,0.f,0.f,0.f}, acc2 = {0.f,0.f,0.f,0.f};
  // B fragments: two statically-named buffers, NEVER runtime-indexed.
  H8u B0h0, B0h1, B0h2, B0h3, B0l0, B0l1, B0l2, B0l3;
  H8u B1h0, B1h1, B1h2, B1h3, B1l0, B1l1, B1l2, B1l3;
  const _Float16* bhp = WH + (size_t)(nt * 16 + lm) * 3072 + quad * 8;
  const _Float16* blp = WL + (size_t)(nt * 16 + lm) * 3072 + quad * 8;

#define C1_ISSUE(ch) { c1_load(xn, base, ch, r0i, c0i, v0); \
                       c1_load(xn, base, ch, r1i, c1i, v1); \
                       if (tid < 32) c1_load(xn, base, ch, r2i, c2i, v2); }
#define C1_WRITE(XS) { *(float4*)(&XS[r0i * CP + c0i * 4]) = v0; \
                       *(float4*)(&XS[r1i * CP + c1i * 4]) = v1; \
                       if (tid < 32) *(float4*)(&XS[r2i * CP + c2i * 4]) = v2; }
#define C1_STAGE2(XS, AH, AL) { _Pragma("unroll") \
  for (int it = 0; it < 4; ++it) { \
    int slot = it * 256 + tid; int ci = slot & 31, m = slot >> 5; \
    const float* xr = &XS[ci * CP + 2 * m]; \
    P4u ph, pl; \
    splitf(xr[0], ph.e[0], pl.e[0]); splitf(xr[1], ph.e[1], pl.e[1]); \
    splitf(xr[2], ph.e[2], pl.e[2]); splitf(xr[3], ph.e[3], pl.e[3]); \
    *(int2*)(&AH[m * AP + ci * 4]) = ph.u; \
    *(int2*)(&AL[m * AP + ci * 4]) = pl.u; } }
#define C1_ISSUEB(ch, P) { \
    P##h0.i = *(const int4*)(bhp + (ch) * 128 +  0); \
    P##h1.i = *(const int4*)(bhp + (ch) * 128 + 32); \
    P##h2.i = *(const int4*)(bhp + (ch) * 128 + 64); \
    P##h3.i = *(const int4*)(bhp + (ch) * 128 + 96); \
    P##l0.i = *(const int4*)(blp + (ch) * 128 +  0); \
    P##l1.i = *(const int4*)(blp + (ch) * 128 + 32); \
    P##l2.i = *(const int4*)(blp + (ch) * 128 + 64); \
    P##l3.i = *(const int4*)(blp + (ch) * 128 + 96); }
#define C1_MFMA1(AH, AL, KS, BH, BL) { \
    H8u ah, al; \
    ah.i = *(const int4*)(&AH[(mt * 16 + lm) * AP + (KS) * 32 + quad * 8]); \
    al.i = *(const int4*)(&AL[(mt * 16 + lm) * AP + (KS) * 32 + quad * 8]); \
    acc1 = __builtin_amdgcn_mfma_f32_16x16x32_f16(ah.h, BH.h, acc1, 0, 0, 0); \
    acc2 = __builtin_amdgcn_mfma_f32_16x16x32_f16(ah.h, BL.h, acc2, 0, 0, 0); \
    acc2 = __builtin_amdgcn_mfma_f32_16x16x32_f16(al.h, BH.h, acc2, 0, 0, 0); }
#define C1_MFMA(AH, AL, P) { C1_MFMA1(AH, AL, 0, P##h0, P##l0) \
                             C1_MFMA1(AH, AL, 1, P##h1, P##l1) \
                             C1_MFMA1(AH, AL, 2, P##h2, P##l2) \
                             C1_MFMA1(AH, AL, 3, P##h3, P##l3) }

  // prologue: chunk 0 staged into buffer0, chunk-1 x in regs, B0 loaded
  C1_ISSUE(0); C1_WRITE(xs0);
  __syncthreads();
  C1_STAGE2(xs0, Ah0, Al0);
  C1_ISSUE(1);
  C1_ISSUEB(0, B0);
  __syncthreads();
#pragma unroll 1
  for (int c = 0; c < NCH; c += 2) {
    // --- even chunk: compute buffer0, stage c+1 into buffer1 ---
    C1_MFMA(Ah0, Al0, B0);
    C1_WRITE(xs1);
    __syncthreads();
    C1_STAGE2(xs1, Ah1, Al1);
    if (c + 2 < NCH) C1_ISSUE(c + 2);
    C1_ISSUEB(c + 1, B1);
    __syncthreads();
    // --- odd chunk: compute buffer1, stage c+2 into buffer0 ---
    C1_MFMA(Ah1, Al1, B1);
    if (c + 2 < NCH) {
      C1_WRITE(xs0);
      __syncthreads();
      C1_STAGE2(xs0, Ah0, Al0);
      if (c + 3 < NCH) C1_ISSUE(c + 3);
      C1_ISSUEB(c + 2, B0);
      __syncthreads();
    }
  }
  // epilogue: relu(acc + bias)
  {
    int col = nt * 16 + lm;
    float bv = bias[col];
    float4 o;
    o.x = fmaxf(acc1[0] + acc2[0] * INV2048 + bv, 0.f);
    o.y = fmaxf(acc1[1] + acc2[1] * INV2048 + bv, 0.f);
    o.z = fmaxf(acc1[2] + acc2[2] * INV2048 + bv, 0.f);
    o.w = fmaxf(acc1[3] + acc2[3] * INV2048 + bv, 0.f);
    *(float4*)(out + ((size_t)n * 32 + col) * 2048 + m0 + mt * 16 + quad * 4) = o;
  }
#undef C1_ISSUE
#undef C1_WRITE
#undef C1_STAGE2
#undef C1_ISSUEB
#undef C1_MFMA1
#undef C1_MFMA
}

// ------------------- generic one-shot MFMA conv (M-tile 32) -----------------
template<int CI, int KP, int NT, int STRIDE,
         bool RELU_IN, bool RELU_OUT, bool BIAS, bool TPOSE, bool RESBLK>
__global__ __launch_bounds__(256) void gconv(
    const float* __restrict__ in, const _Float16* __restrict__ WH,
    const _Float16* __restrict__ WL, const float* __restrict__ bias,
    const _Float16* __restrict__ W2H, const _Float16* __restrict__ W2L,
    float* __restrict__ out, int Lin, int Lout) {
  constexpr int CP = 32 * STRIDE + 4;
  constexpr int CP4 = CP / 4;
  constexpr int AP = KP + 8;
  constexpr int KS = KP / 32;
  constexpr int NTW = (NT == 2) ? 1 : NT / 2;
  __shared__ float xs[CI * CP];
  __shared__ _Float16 Ah[32 * AP];
  __shared__ _Float16 Al[32 * AP];
  __shared__ _Float16 A2h[RESBLK ? 32 * 40 : 1];
  __shared__ _Float16 A2l[RESBLK ? 32 * 40 : 1];
  const int tid = threadIdx.x;
  const int w = tid >> 6, lane = tid & 63, lm = lane & 15, quad = lane >> 4;
  const int mt = w >> 1, ntb = (w & 1) * NTW;
  const int m0 = blockIdx.x * 32, n = blockIdx.y;
  const int base = m0 * STRIDE - 1;
  const float* inN = in + (size_t)n * CI * Lin;
  constexpr int SLOTS = CI * CP4;
#pragma unroll
  for (int it = 0; it < (SLOTS + 255) / 256; ++it) {
    int idx = it * 256 + tid;
    if (idx < SLOTS) {
      int row = idx / CP4, c4 = idx % CP4;
      int p0 = base + c4 * 4;
      const float* rp = inN + (size_t)row * Lin;
      float4 v;
      if (p0 >= 0 && p0 + 3 < Lin) v = *(const float4*)(rp + p0);
      else {
        v.x = (p0   >= 0 && p0   < Lin) ? rp[p0]   : 0.f;
        v.y = (p0+1 >= 0 && p0+1 < Lin) ? rp[p0+1] : 0.f;
        v.z = (p0+2 >= 0 && p0+2 < Lin) ? rp[p0+2] : 0.f;
        v.w = (p0+3 >= 0 && p0+3 < Lin) ? rp[p0+3] : 0.f;
      }
      *(float4*)(&xs[row * CP + c4 * 4]) = v;
    }
  }
  __syncthreads();
#pragma unroll
  for (int it = 0; it < (32 * CI) / 256; ++it) {
    int slot = it * 256 + tid;
    int ci = slot & (CI - 1), m = slot / CI;
    const float* xr = &xs[ci * CP + STRIDE * m];
    float a0 = xr[0], a1 = xr[1], a2 = xr[2], a3 = xr[3];
    if (RELU_IN) { a0 = fmaxf(a0,0.f); a1 = fmaxf(a1,0.f);
                   a2 = fmaxf(a2,0.f); a3 = fmaxf(a3,0.f); }
    P4u ph, pl;
    splitf(a0, ph.e[0], pl.e[0]); splitf(a1, ph.e[1], pl.e[1]);
    splitf(a2, ph.e[2], pl.e[2]); splitf(a3, ph.e[3], pl.e[3]);
    *(int2*)(&Ah[m * AP + ci * 4]) = ph.u;
    *(int2*)(&Al[m * AP + ci * 4]) = pl.u;
  }
  __syncthreads();
  f32x4 acc1[NTW], acc2[NTW];
#pragma unroll
  for (int j = 0; j < NTW; ++j)
#pragma unroll
    for (int r = 0; r < 4; ++r) { acc1[j][r] = 0.f; acc2[j][r] = 0.f; }
  H8u bh[2][NTW], bl[2][NTW];
#pragma unroll
  for (int j = 0; j < NTW; ++j) {
    int col = (ntb + j) * 16 + lm;
    bh[0][j].i = *(const int4*)(WH + (size_t)col * KP + quad * 8);
    bl[0][j].i = *(const int4*)(WL + (size_t)col * KP + quad * 8);
  }
#pragma unroll
  for (int ks = 0; ks < KS; ++ks) {
    int cur = ks & 1;                      // static after full unroll
    if (ks + 1 < KS) {
#pragma unroll
      for (int j = 0; j < NTW; ++j) {
        int col = (ntb + j) * 16 + lm;
        bh[cur ^ 1][j].i = *(const int4*)(WH + (size_t)col * KP + (ks+1) * 32 + quad * 8);
        bl[cur ^ 1][j].i = *(const int4*)(WL + (size_t)col * KP + (ks+1) * 32 + quad * 8);
      }
    }
    H8u ah, al;
    ah.i = *(const int4*)(&Ah[(mt * 16 + lm) * AP + ks * 32 + quad * 8]);
    al.i = *(const int4*)(&Al[(mt * 16 + lm) * AP + ks * 32 + quad * 8]);
#pragma unroll
    for (int j = 0; j < NTW; ++j) {
      acc1[j] = __builtin_amdgcn_mfma_f32_16x16x32_f16(ah.h, bh[cur][j].h, acc1[j], 0,0,0);
      acc2[j] = __builtin_amdgcn_mfma_f32_16x16x32_f16(ah.h, bl[cur][j].h, acc2[j], 0,0,0);
      acc2[j] = __builtin_amdgcn_mfma_f32_16x16x32_f16(al.h, bh[cur][j].h, acc2[j], 0,0,0);
    }
  }
  if (RESBLK) {
    int co2 = (w & 1) * 16 + lm;
#pragma unroll
    for (int r = 0; r < 4; ++r) {
      float hv = fmaxf(acc1[0][r] + acc2[0][r] * INV2048, 0.f);
      _Float16 hh, hl; splitf(hv, hh, hl);
      int m = mt * 16 + quad * 4 + r;
      A2h[m * 40 + co2] = hh; A2l[m * 40 + co2] = hl;
    }
    __syncthreads();
    f32x4 c1[2], c2[2];
#pragma unroll
    for (int j = 0; j < 2; ++j)
#pragma unroll
      for (int r = 0; r < 4; ++r) { c1[j][r] = 0.f; c2[j][r] = 0.f; }
    H8u a2h, a2l;
    a2h.i = *(const int4*)(&A2h[(mt * 16 + lm) * 40 + quad * 8]);
    a2l.i = *(const int4*)(&A2l[(mt * 16 + lm) * 40 + quad * 8]);
    int ntb2 = (w & 1) * 2;
#pragma unroll
    for (int j = 0; j < 2; ++j) {
      int col = (ntb2 + j) * 16 + lm;
      H8u wbh, wbl;
      wbh.i = *(const int4*)(W2H + col * 32 + quad * 8);
      wbl.i = *(const int4*)(W2L + col * 32 + quad * 8);
      c1[j] = __builtin_amdgcn_mfma_f32_16x16x32_f16(a2h.h, wbh.h, c1[j], 0,0,0);
      c2[j] = __builtin_amdgcn_mfma_f32_16x16x32_f16(a2h.h, wbl.h, c2[j], 0,0,0);
      c2[j] = __builtin_amdgcn_mfma_f32_16x16x32_f16(a2l.h, wbh.h, c2[j], 0,0,0);
    }
#pragma unroll
    for (int j = 0; j < 2; ++j) {
      int col = (ntb2 + j) * 16 + lm;
      float4 o;
#pragma unroll
      for (int r = 0; r < 4; ++r) {
        int m = mt * 16 + quad * 4 + r;
        float res = xs[col * CP + m + 1];
        ((float*)&o)[r] = res + c1[j][r] + c2[j][r] * INV2048;
      }
      *(float4*)(out + ((size_t)n * 64 + col) * Lout + m0 + mt * 16 + quad * 4) = o;
    }
  } else {
    constexpr int CO = TPOSE ? NT * 8 : NT * 16;
#pragma unroll
    for (int j = 0; j < NTW; ++j) {
      int col = (ntb + j) * 16 + lm;
      int par = TPOSE ? (col / CO) : 0;
      int co  = TPOSE ? (col % CO) : col;
      float bv = BIAS ? bias[co] : 0.f;
      float vr[4];
#pragma unroll
      for (int r = 0; r < 4; ++r) {
        float v = acc1[j][r] + acc2[j][r] * INV2048 + bv;
        vr[r] = RELU_OUT ? fmaxf(v, 0.f) : v;
      }
      if (TPOSE) {
#pragma unroll
        for (int r = 0; r < 4; ++r) {
          int m = m0 + mt * 16 + quad * 4 + r;
          out[((size_t)n * CO + co) * Lout + 2 * m + par] = vr[r];
        }
      } else {
        float4 o; o.x = vr[0]; o.y = vr[1]; o.z = vr[2]; o.w = vr[3];
        *(float4*)(out + ((size_t)n * CO + co) * Lout + m0 + mt * 16 + quad * 4) = o;
      }
    }
  }
}

// ------------------------------ codebook norms ------------------------------
__global__ void enorm_k(const float* __restrict__ emb, float* __restrict__ en) {
  int e = blockIdx.x * blockDim.x + threadIdx.x;
  if (e >= 512) return;
  float s = 0.f;
  const float* r = emb + (size_t)e * 64;
  for (int c = 0; c < 64; ++c) s = fmaf(r[c], r[c], s);
  en[e] = s;
}

// ------------------ fused prevq (1x1, relu-in) + VQ -------------------------
__global__ __launch_bounds__(256) void vq_fused(
    const float* __restrict__ sIn, const _Float16* __restrict__ PQH,
    const _Float16* __restrict__ PQL, const float* __restrict__ pqb,
    const float* __restrict__ emb, const float* __restrict__ en,
    float* __restrict__ q) {
  __shared__ float xs[64 * 68];
  __shared__ _Float16 Ah[64 * 72];
  __shared__ _Float16 Al[64 * 72];
  __shared__ float zl[64 * 65];
  __shared__ float dred[4 * 64];
  __shared__ int   ired[4 * 64];
  __shared__ int   idxs[64];
  const int tid = threadIdx.x;
  const int w = tid >> 6, lane = tid & 63, lm = lane & 15, quad = lane >> 4;
  const int n = blockIdx.y, t0 = blockIdx.x * 64;
#pragma unroll
  for (int it = 0; it < 4; ++it) {
    int idx = it * 256 + tid;
    int row = idx >> 4, c4 = idx & 15;
    float4 v = *(const float4*)(sIn + ((size_t)n * 64 + row) * 1024 + t0 + c4 * 4);
    *(float4*)(&xs[row * 68 + c4 * 4]) = v;
  }
  __syncthreads();
#pragma unroll
  for (int it = 0; it < 16; ++it) {
    int slot = it * 256 + tid;
    int ci = slot & 63, t = slot >> 6;
    float v = fmaxf(xs[ci * 68 + t], 0.f);
    _Float16 h, l; splitf(v, h, l);
    Ah[t * 72 + ci] = h; Al[t * 72 + ci] = l;
  }
  __syncthreads();
  f32x4 a1[4], a2[4];
#pragma unroll
  for (int j = 0; j < 4; ++j)
#pragma unroll
    for (int r = 0; r < 4; ++r) { a1[j][r] = 0.f; a2[j][r] = 0.f; }
#pragma unroll
  for (int ks = 0; ks < 2; ++ks) {
    H8u ah, al;
    ah.i = *(const int4*)(&Ah[(w * 16 + lm) * 72 + ks * 32 + quad * 8]);
    al.i = *(const int4*)(&Al[(w * 16 + lm) * 72 + ks * 32 + quad * 8]);
#pragma unroll
    for (int j = 0; j < 4; ++j) {
      int col = j * 16 + lm;
      H8u bh, bl;
      bh.i = *(const int4*)(PQH + col * 64 + ks * 32 + quad * 8);
      bl.i = *(const int4*)(PQL + col * 64 + ks * 32 + quad * 8);
      a1[j] = __builtin_amdgcn_mfma_f32_16x16x32_f16(ah.h, bh.h, a1[j], 0,0,0);
      a2[j] = __builtin_amdgcn_mfma_f32_16x16x32_f16(ah.h, bl.h, a2[j], 0,0,0);
      a2[j] = __builtin_amdgcn_mfma_f32_16x16x32_f16(al.h, bh.h, a2[j], 0,0,0);
    }
  }
#pragma unroll
  for (int j = 0; j < 4; ++j) {
    int col = j * 16 + lm;
    float bv = pqb[col];
#pragma unroll
    for (int r = 0; r < 4; ++r) {
      int t = w * 16 + quad * 4 + r;
      zl[t * 65 + col] = a1[j][r] + a2[j][r] * INV2048 + bv;
    }
  }
  __syncthreads();
  int tt = tid & 63, cq = tid >> 6;
  float zv[64];
#pragma unroll
  for (int c = 0; c < 64; ++c) zv[c] = zl[tt * 65 + c];
  float best = 1e30f; int bidx = 0;
  for (int e = cq * 128; e < cq * 128 + 128; ++e) {
    const float* er = emb + (size_t)e * 64;
    float dot = 0.f;
#pragma unroll
    for (int c = 0; c < 64; ++c) dot = fmaf(zv[c], er[c], dot);
    float d = en[e] - 2.f * dot;
    if (d < best) { best = d; bidx = e; }
  }
  dred[cq * 64 + tt] = best;
  ired[cq * 64 + tt] = bidx;
  __syncthreads();
  if (cq == 0) {
    for (int j = 1; j < 4; ++j) {
      float d = dred[j * 64 + tt]; int i2 = ired[j * 64 + tt];
      if (d < best || (d == best && i2 < bidx)) { best = d; bidx = i2; }
    }
    idxs[tt] = bidx;
  }
  __syncthreads();
  for (int it = 0; it < 16; ++it) {
    int c = cq * 16 + it;
    q[((size_t)n * 64 + c) * 1024 + t0 + tt] = emb[(size_t)idxs[tt] * 64 + c];
  }
}

// ---------------------------------------------------------------------------
extern "C" void kernel_launch(void* const* d_in, const int* in_sizes, int n_in,
                              void* d_out, int out_size, void* d_ws, size_t ws_size,
                              hipStream_t stream) {
  const float* x        = (const float*)d_in[0];
  const float* enc_b1   = (const float*)d_in[2];
  const float* enc_b2   = (const float*)d_in[4];
  const float* enc_b3   = (const float*)d_in[6];
  const float* prevq_b  = (const float*)d_in[12];
  const float* emb      = (const float*)d_in[13];
  const float* dec_b1   = (const float*)d_in[15];
  const float* dect1_b  = (const float*)d_in[21];
  const float* dect2_b  = (const float*)d_in[23];
  float* out = (float*)d_out;

  WPtrs P;
  P.c1  = (const float*)d_in[1];  P.c2  = (const float*)d_in[3];
  P.c3  = (const float*)d_in[5];  P.er0a = (const float*)d_in[7];
  P.er0b = (const float*)d_in[8]; P.er1a = (const float*)d_in[9];
  P.er1b = (const float*)d_in[10]; P.pq = (const float*)d_in[11];
  P.dw1 = (const float*)d_in[14]; P.dr0a = (const float*)d_in[16];
  P.dr0b = (const float*)d_in[17]; P.dr1a = (const float*)d_in[18];
  P.dr1b = (const float*)d_in[19]; P.t1 = (const float*)d_in[20];
  P.t2  = (const float*)d_in[22];

  float* A  = (float*)d_ws;                   // 1M floats
  float* B  = A + (1u << 20);                 // 1M floats
  float* EN = B + (1u << 20);                 // 512 floats
  _Float16* WH = (_Float16*)(EN + 1024);      // WTOT f16
  _Float16* WL = WH + WTOT;

  dim3 blk(256);
  prep_k<<<dim3((WTOT + 255) / 256), blk, 0, stream>>>(P, WH, WL);
  enorm_k<<<dim3(2), blk, 0, stream>>>(emb, EN);
  // encoder
  conv1_k<<<dim3(64, 16), blk, 0, stream>>>(x, WH + OFF_C1, WL + OFF_C1, enc_b1, A);
  gconv<32,128,4,2, false,true,true, false,false><<<dim3(32,16), blk, 0, stream>>>(
      A, WH+OFF_C2, WL+OFF_C2, enc_b2, nullptr, nullptr, B, 2048, 1024);
  gconv<64,256,4,1, false,false,true, false,false><<<dim3(32,16), blk, 0, stream>>>(
      B, WH+OFF_C3, WL+OFF_C3, enc_b3, nullptr, nullptr, A, 1024, 1024);
  gconv<64,256,2,1, true,false,false, false,true><<<dim3(32,16), blk, 0, stream>>>(
      A, WH+OFF_ER0A, WL+OFF_ER0A, nullptr, WH+OFF_ER0B, WL+OFF_ER0B, B, 1024, 1024);
  gconv<64,256,2,1, true,false,false, false,true><<<dim3(32,16), blk, 0, stream>>>(
      B, WH+OFF_ER1A, WL+OFF_ER1A, nullptr, WH+OFF_ER1B, WL+OFF_ER1B, A, 1024, 1024);
  // VQ (prevq + relu fused)
  vq_fused<<<dim3(16,16), blk, 0, stream>>>(A, WH+OFF_PQ, WL+OFF_PQ, prevq_b, emb, EN, B);
  // decoder
  gconv<64,256,4,1, false,false,true, false,false><<<dim3(32,16), blk, 0, stream>>>(
      B, WH+OFF_DW1, WL+OFF_DW1, dec_b1, nullptr, nullptr, A, 1024, 1024);
  gconv<64,256,2,1, true,false,false, false,true><<<dim3(32,16), blk, 0, stream>>>(
      A, WH+OFF_DR0A, WL+OFF_DR0A, nullptr, WH+OFF_DR0B, WL+OFF_DR0B, B, 1024, 1024);
  gconv<64,256,2,1, true,false,false, false,true><<<dim3(32,16), blk, 0, stream>>>(
      B, WH+OFF_DR1A, WL+OFF_DR1A, nullptr, WH+OFF_DR1B, WL+OFF_DR1B, A, 1024, 1024);
  gconv<64,256,4,1, true,true,true, true,false><<<dim3(32,16), blk, 0, stream>>>(
      A, WH+OFF_T1, WL+OFF_T1, dect1_b, nullptr, nullptr, B, 1024, 2048);
  gconv<32,128,8,1, false,false,true, true,false><<<dim3(64,16), blk, 0, stream>>>(
      B, WH+OFF_T2, WL+OFF_T2, dect2_b, nullptr, nullptr, out, 2048, 4096);
}